// Round 9
// baseline (789.386 us; speedup 1.0000x reference)
//
#include <hip/hip_runtime.h>
#include <hip/hip_bf16.h>

typedef __bf16 bf16x8 __attribute__((ext_vector_type(8)));
typedef float  f32x4  __attribute__((ext_vector_type(4)));
typedef unsigned short u16;
typedef unsigned short u16x4 __attribute__((ext_vector_type(4)));
typedef unsigned int   u32;
typedef unsigned long long u64;

#define NB 1024
#define NS 1024
#define NI 32
#define NH 128
#define NCH (NS / 8)

// u64-unit strides
#define HBH   (16 * 17 * 2)   // one h ping-pong half
#define XSLOT (4 * 17 * 2)    // one x step-slot
#define XHALF (8 * XSLOT)     // one x chunk buffer

__device__ __forceinline__ u64 pack4_bf16(f32x4 v) {
  u16x4 p;
#pragma unroll
  for (int r = 0; r < 4; ++r) p[r] = __builtin_bit_cast(u16, (__bf16)v[r]);
  return __builtin_bit_cast(u64, p);
}

__device__ __forceinline__ bf16x8 cvt8(f32x4 a, f32x4 b) {
  bf16x8 u;
#pragma unroll
  for (int j = 0; j < 4; ++j) { u[j] = (__bf16)a[j]; u[4 + j] = (__bf16)b[j]; }
  return u;
}

// Fused gate math, 3 trans ops per element (verified absmax 0.0099 in R7/R8):
//   z·(hh−h) = [(f−1) − h(f+1)] / [(1+e)(f+1)],  e = e^{−az}, f = e^{2·ah}
__device__ __forceinline__ f32x4 gru_elem(f32x4 az, f32x4 ah, f32x4 h) {
  const float NL2E  = -1.4426950408889634f;
  const float P2L2E =  2.8853900817779268f;
  f32x4 hn;
#pragma unroll
  for (int r = 0; r < 4; ++r) {
    float a  = fminf(15.f, fmaxf(-15.f, az[r]));
    float b  = fminf(15.f, fmaxf(-15.f, ah[r]));
    float e  = __builtin_amdgcn_exp2f(a * NL2E);
    float f  = __builtin_amdgcn_exp2f(b * P2L2E);
    float fp = f + 1.f;
    float num = __builtin_fmaf(-h[r], fp, f - 1.f);
    float den = (1.f + e) * fp;
    float rr  = __builtin_amdgcn_rcpf(den);
    hn[r] = __builtin_fmaf(num, rr, h[r]);
  }
  return hn;
}

// Spin until both flags of a producer pair reach tgt. Returns 0, data-dependent
// on the final flag reads (add to data addresses: blocks read-hoisting above poll).
__device__ __forceinline__ u32 poll2(const volatile u32* f, u32 tgt) {
  u32 a = f[0], b = f[1];
  while (a < tgt || b < tgt) { a = f[0]; b = f[1]; }
  u32 z;
  asm("v_and_b32 %0, 0, %1" : "=v"(z) : "v"(a ^ b));
  return z;
}

// Block: 512 threads = 8 waves (2/SIMD). Block owns 16 batch rows for the scan.
// Wave w computes hidden cols [16w, 16w+16).
// NO per-step barrier: per-wave-pair LDS sequence flags. B-fragment kt depends
// only on hidden cols 32kt..32kt+31 = the slice written by waves 2kt, 2kt+1, so
// each wave polls one pair-flag per fragment (rotated start kt = w>>1) and waves
// self-stagger, letting MFMA / LDS / trans pipes overlap instead of phase-summing.
// Producer: ds_write slice -> lgkmcnt(0) -> flag = t+1.  Depth-2 h ping-pong is
// safe: all 4 polls (>= t) precede the h(t+1) write.
// x chunks (8 steps) live in LDS double-buffer; wave w stages step-slot w of the
// next chunk during its own step tt==6 (loads issued tt==4); visibility piggybacks
// on the h-flags (>= 2-step lead).
__global__ __launch_bounds__(512, 1) void gru_scan(
    const float* __restrict__ x,
    const float* __restrict__ Wz, const float* __restrict__ Uz, const float* __restrict__ bz,
    const float* __restrict__ Wh, const float* __restrict__ Uh, const float* __restrict__ bh,
    float* __restrict__ out)
{
  __shared__ __align__(16) u64 hb[2][16][17][2];     // 8.5 KB, k-major + pad
  __shared__ __align__(16) u64 hx[2][8][4][17][2];   // 17 KB,  k-major + pad
  __shared__ u32 fl[4][32];                          // pair-flags (padded rows)

  const int tid  = threadIdx.x;
  const int lane = tid & 63;
  const int w    = tid >> 6;     // wave 0..7
  const int ml   = lane & 15;    // batch row in tile
  const int g    = lane >> 4;    // k-group / reg-group
  const int rb   = blockIdx.x * 16;
  const int s0   = w >> 1;       // starting k-slice (own pair)

  // ---- persistent weight fragments, k-slices ROTATED so frag i = slice (s0+i)&3 ----
  bf16x8 ufz[4], ufh[4];
  bf16x8 wfz, wfh;
  f32x4  biasz, biash;
  {
    const int n0 = 16 * w + ml;
#pragma unroll
    for (int i = 0; i < 4; ++i) {
      const int kt = (s0 + i) & 3;
#pragma unroll
      for (int j = 0; j < 8; ++j) {
        ufz[i][j] = (__bf16)Uz[(32 * kt + 8 * g + j) * NH + n0];
        ufh[i][j] = (__bf16)Uh[(32 * kt + 8 * g + j) * NH + n0];
      }
    }
#pragma unroll
    for (int j = 0; j < 8; ++j) {
      wfz[j] = (__bf16)Wz[(8 * g + j) * NH + n0];
      wfh[j] = (__bf16)Wh[(8 * g + j) * NH + n0];
    }
    const int nb = 16 * w + 4 * g;
#pragma unroll
    for (int r = 0; r < 4; ++r) { biasz[r] = bz[nb + r]; biash[r] = bh[nb + r]; }
  }

  // zero h(0) (slot 0) and flags
  for (int i = tid; i < HBH; i += 512) ((u64*)hb)[i] = 0ULL;
  if (tid < 128) ((u32*)fl)[tid] = 0u;

  // ---- pointers (all static from here on) ----
  const u64* hb0 = &hb[0][0][0][0];
  const u64* rp0 = hb0 + (4 * ((s0 + 0) & 3) + g) * 34 + ml * 2;
  const u64* rp1 = hb0 + (4 * ((s0 + 1) & 3) + g) * 34 + ml * 2;
  const u64* rp2 = hb0 + (4 * ((s0 + 2) & 3) + g) * 34 + ml * 2;
  const u64* rp3 = hb0 + (4 * ((s0 + 3) & 3) + g) * 34 + ml * 2;
  u64*       wp  = (u64*)hb0 + (2 * w + (g >> 1)) * 34 + ml * 2 + (g & 1);
  u64*       hx0 = &hx[0][0][0][0][0];
  const int  xoff = (g * 17 + ml) * 2;
  const volatile u32* fp0 = &fl[(s0 + 0) & 3][0];
  const volatile u32* fp1 = &fl[(s0 + 1) & 3][0];
  const volatile u32* fp2 = &fl[(s0 + 2) & 3][0];
  const volatile u32* fp3 = &fl[(s0 + 3) & 3][0];
  volatile u32* fmy = &fl[w >> 1][w & 1];

  // ---- prologue: stage chunk 0, step-slot w ----
  {
    const float* ps = x + ((size_t)(rb + ml) * NS + w) * NI + 8 * g;
    f32x4 a = ((const f32x4*)ps)[0];
    f32x4 b = ((const f32x4*)ps)[1];
    *(bf16x8*)(hx0 + w * XSLOT + xoff) = cvt8(a, b);
  }
  __syncthreads();   // the ONLY barrier: zeros + chunk-0 staging visible

  f32x4 hv = {0.f, 0.f, 0.f, 0.f};
  float* optr = out + (size_t)(rb + ml) * NS * NH + 16 * w + 4 * g;
  const f32x4 zero4 = {0.f, 0.f, 0.f, 0.f};
  f32x4 vxa, vxb;
  int tcur = 0;

  // ax(0)
  f32x4 axz, axh;
  {
    bf16x8 xf = *(const bf16x8*)(hx0 + xoff);
    axz = __builtin_amdgcn_mfma_f32_16x16x32_bf16(wfz, xf, biasz, 0, 0, 0);
    axh = __builtin_amdgcn_mfma_f32_16x16x32_bf16(wfh, xf, biash, 0, 0, 0);
  }

  // One step: P = t&1, XB = chunk&1 (both compile-time in the unrolled body).
  // Frag i <- slice (s0+i)&3, gated by pair-flag i.
#define GRU_STEP(P, XB, TT, MORE_, CNEXT)                                                  \
  {                                                                                        \
    u32 z0 = poll2(fp0, (u32)tcur);                                                        \
    bf16x8 f0 = *(const bf16x8*)(rp0 + (P) * HBH + z0);                                    \
    u32 z1 = poll2(fp1, (u32)tcur);                                                        \
    bf16x8 f1 = *(const bf16x8*)(rp1 + (P) * HBH + z1);                                    \
    f32x4 cza = __builtin_amdgcn_mfma_f32_16x16x32_bf16(ufz[0], f0, axz, 0, 0, 0);         \
    f32x4 cha = __builtin_amdgcn_mfma_f32_16x16x32_bf16(ufh[0], f0, axh, 0, 0, 0);         \
    u32 z2 = poll2(fp2, (u32)tcur);                                                        \
    bf16x8 f2 = *(const bf16x8*)(rp2 + (P) * HBH + z2);                                    \
    cza = __builtin_amdgcn_mfma_f32_16x16x32_bf16(ufz[1], f1, cza, 0, 0, 0);               \
    cha = __builtin_amdgcn_mfma_f32_16x16x32_bf16(ufh[1], f1, cha, 0, 0, 0);               \
    u32 z3 = poll2(fp3, (u32)tcur);                                                        \
    bf16x8 f3 = *(const bf16x8*)(rp3 + (P) * HBH + z3);                                    \
    /* x frag for t+1: visible once all pair-flags >= t (staged >= 2 steps ago) */         \
    bf16x8 xf = *(const bf16x8*)(hx0 + (((TT) == 7) ? ((XB) ^ 1) : (XB)) * XHALF +         \
                                 ((((TT) + 1) & 7)) * XSLOT + xoff + z3);                  \
    f32x4 czb = __builtin_amdgcn_mfma_f32_16x16x32_bf16(ufz[2], f2, zero4, 0, 0, 0);       \
    f32x4 chb = __builtin_amdgcn_mfma_f32_16x16x32_bf16(ufh[2], f2, zero4, 0, 0, 0);       \
    czb = __builtin_amdgcn_mfma_f32_16x16x32_bf16(ufz[3], f3, czb, 0, 0, 0);               \
    chb = __builtin_amdgcn_mfma_f32_16x16x32_bf16(ufh[3], f3, chb, 0, 0, 0);               \
    if ((TT) == 4 && (MORE_)) {  /* issue next-chunk loads for own slot (2-step lead) */   \
      const float* ps = x + ((size_t)(rb + ml) * NS + 8 * (CNEXT) + w) * NI + 8 * g;       \
      vxa = ((const f32x4*)ps)[0];                                                         \
      vxb = ((const f32x4*)ps)[1];                                                         \
    }                                                                                      \
    axz = __builtin_amdgcn_mfma_f32_16x16x32_bf16(wfz, xf, biasz, 0, 0, 0);                \
    axh = __builtin_amdgcn_mfma_f32_16x16x32_bf16(wfh, xf, biash, 0, 0, 0);                \
    const f32x4 az = cza + czb;                                                            \
    const f32x4 ah = cha + chb;                                                            \
    f32x4 hn = gru_elem(az, ah, hv);                                                       \
    hv = hn;                                                                               \
    *(wp + ((P) ^ 1) * HBH) = pack4_bf16(hn);                                              \
    if ((TT) == 6 && (MORE_)) {  /* stage own slot of next chunk (z3: after polls) */      \
      *(bf16x8*)(hx0 + (((XB) ^ 1)) * XHALF + w * XSLOT + xoff + z3) = cvt8(vxa, vxb);     \
    }                                                                                      \
    __builtin_nontemporal_store(hn, (f32x4*)optr);                                         \
    optr += NH;                                                                            \
    asm volatile("s_waitcnt lgkmcnt(0)" ::: "memory");                                     \
    __builtin_amdgcn_sched_barrier(0);                                                     \
    if (lane == 0) *fmy = (u32)(tcur + 1);                                                 \
    ++tcur;                                                                                \
  }

  for (int cp = 0; cp < NCH; cp += 2) {
    const bool more1 = (cp + 2 < NCH);
    // even chunk (XB = 0), stages chunk cp+1 (always exists)
    GRU_STEP(0, 0, 0, true, cp + 1)
    GRU_STEP(1, 0, 1, true, cp + 1)
    GRU_STEP(0, 0, 2, true, cp + 1)
    GRU_STEP(1, 0, 3, true, cp + 1)
    GRU_STEP(0, 0, 4, true, cp + 1)
    GRU_STEP(1, 0, 5, true, cp + 1)
    GRU_STEP(0, 0, 6, true, cp + 1)
    GRU_STEP(1, 0, 7, true, cp + 1)
    // odd chunk (XB = 1), stages chunk cp+2 (if any)
    GRU_STEP(0, 1, 0, more1, cp + 2)
    GRU_STEP(1, 1, 1, more1, cp + 2)
    GRU_STEP(0, 1, 2, more1, cp + 2)
    GRU_STEP(1, 1, 3, more1, cp + 2)
    GRU_STEP(0, 1, 4, more1, cp + 2)
    GRU_STEP(1, 1, 5, more1, cp + 2)
    GRU_STEP(0, 1, 6, more1, cp + 2)
    GRU_STEP(1, 1, 7, more1, cp + 2)
  }

  // h_last
  const size_t lbase = (size_t)NB * NS * NH + (size_t)(rb + ml) * NH + 16 * w + 4 * g;
  *(f32x4*)(out + lbase) = hv;
}

extern "C" void kernel_launch(void* const* d_in, const int* in_sizes, int n_in,
                              void* d_out, int out_size, void* d_ws, size_t ws_size,
                              hipStream_t stream) {
  const float* x  = (const float*)d_in[0];
  // d_in[1..3] = W_r, U_r, b_r: unused (r gate never affects the output)
  const float* Wz = (const float*)d_in[4];
  const float* Uz = (const float*)d_in[5];
  const float* bz = (const float*)d_in[6];
  const float* Wh = (const float*)d_in[7];
  const float* Uh = (const float*)d_in[8];
  const float* bh = (const float*)d_in[9];
  float* out = (float*)d_out;

  gru_scan<<<dim3(NB / 16), dim3(512), 0, stream>>>(x, Wz, Uz, bz, Wh, Uh, bh, out);
}

// Round 10
// 500.849 us; speedup vs baseline: 1.5761x; 1.5761x over previous
//
#include <hip/hip_runtime.h>
#include <hip/hip_bf16.h>

typedef __bf16 bf16x8 __attribute__((ext_vector_type(8)));
typedef float  f32x4  __attribute__((ext_vector_type(4)));
typedef unsigned short u16;
typedef unsigned short u16x4 __attribute__((ext_vector_type(4)));
typedef unsigned long long u64;

#define NB 1024
#define NS 1024
#define NI 32
#define NH 128

__device__ __forceinline__ u64 pack4_bf16(f32x4 v) {
  u16x4 p;
#pragma unroll
  for (int r = 0; r < 4; ++r) p[r] = __builtin_bit_cast(u16, (__bf16)v[r]);
  return __builtin_bit_cast(u64, p);
}

// Barrier that drains lgkmcnt only (no vmcnt): global stores stay in flight.
__device__ __forceinline__ void lds_barrier() {
  __builtin_amdgcn_sched_barrier(0);
  asm volatile("s_waitcnt lgkmcnt(0)" ::: "memory");
  __builtin_amdgcn_s_barrier();
  asm volatile("" ::: "memory");
  __builtin_amdgcn_sched_barrier(0);
}

// Fused gate math, 3 trans ops per element (2 exp2 + 1 shared rcp); verified
// absmax 0.0099 in R7/R8:
//   h' = h + [(f−1) − h(f+1)] / [(1+e)(f+1)],  e = e^{−az}, f = e^{2·ah}
// az/ah clamped to ±15: clamp error ≤3e-7; den ≤ 2^65 (no overflow).
__device__ __forceinline__ f32x4 gru_elem(f32x4 az, f32x4 ah, f32x4 h) {
  const float NL2E  = -1.4426950408889634f;
  const float P2L2E =  2.8853900817779268f;
  f32x4 hn;
#pragma unroll
  for (int r = 0; r < 4; ++r) {
    float a  = fminf(15.f, fmaxf(-15.f, az[r]));
    float b  = fminf(15.f, fmaxf(-15.f, ah[r]));
    float e  = __builtin_amdgcn_exp2f(a * NL2E);
    float f  = __builtin_amdgcn_exp2f(b * P2L2E);
    float fp = f + 1.f;
    float num = __builtin_fmaf(-h[r], fp, f - 1.f);
    float den = (1.f + e) * fp;
    float rr  = __builtin_amdgcn_rcpf(den);
    hn[r] = __builtin_fmaf(num, rr, h[r]);
  }
  return hn;
}

// Block: 512 threads = 8 waves (2/SIMD). Block owns 16 batch rows for the scan.
// Wave w computes hidden cols [16w, 16w+16).  (R3 structure, reordered step.)
// MFMA: D'[n][m] = sum_k U[k][n] * h[m][k]  (A' = U^T slice, B' = h^T)
//   B'-frag: lane l holds h[m=l&15][k = 32kt + 8(l>>4) + j]   (one ds_read_b128)
//   D'     : lane l holds h_new[m=l&15][n = 16w + 4(l>>4) + r]
// h ping-pongs in LDS as bf16, u64 units swizzled by unit ^ ((row&7)<<1).
// Step schedule: reads FIRST, then prev-output store + x staging fill the read
// shadow, then MFMAs (z-gate chains first), elem, h-write, lgkm-only barrier.
__global__ __launch_bounds__(512, 2) void gru_scan(
    const float* __restrict__ x,
    const float* __restrict__ Wz, const float* __restrict__ Uz, const float* __restrict__ bz,
    const float* __restrict__ Wh, const float* __restrict__ Uh, const float* __restrict__ bh,
    float* __restrict__ out)
{
  __shared__ __align__(16) u64    hbuf[2][16][32];       // 8 KB
  __shared__ __align__(16) bf16x8 xbuf[2][8][16][4];     // 16 KB

  const int tid  = threadIdx.x;
  const int lane = tid & 63;
  const int w    = tid >> 6;     // wave 0..7
  const int ml   = lane & 15;    // batch row in tile
  const int g    = lane >> 4;    // k-group / reg-group
  const int rb   = blockIdx.x * 16;

  // ---- persistent weight fragments ----
  bf16x8 ufrag[2][4];   // [gate][kt]
  bf16x8 wfrag[2];      // [gate]
  f32x4  bias2[2];      // [gate], D layout
  {
    const float* Ug[2] = {Uz, Uh};
    const float* Wg[2] = {Wz, Wh};
    const float* bg[2] = {bz, bh};
    const int n0 = 16 * w + ml;   // A'-row = hidden col
#pragma unroll
    for (int gate = 0; gate < 2; ++gate) {
#pragma unroll
      for (int kt = 0; kt < 4; ++kt)
#pragma unroll
        for (int j = 0; j < 8; ++j)
          ufrag[gate][kt][j] = (__bf16)Ug[gate][(32 * kt + 8 * g + j) * NH + n0];
#pragma unroll
      for (int j = 0; j < 8; ++j)
        wfrag[gate][j] = (__bf16)Wg[gate][(8 * g + j) * NH + n0];
      const int nb = 16 * w + 4 * g;
#pragma unroll
      for (int r = 0; r < 4; ++r) bias2[gate][r] = bg[gate][nb + r];
    }
  }

  // h0 = 0
  for (int i = tid; i < 16 * 32; i += 512) hbuf[0][i >> 5][i & 31] = 0ULL;

  // ---- x staging: thread (r_st, c8) handles 8 consecutive floats (one 16B unit) ----
  const int r_st  = tid >> 5;          // 0..15
  const int c8    = tid & 31;          // 0..31 -> tt = c8>>2, unit = c8&3
  const int tt_st = c8 >> 2;
  const int un_st = (c8 & 3) ^ (r_st & 3);
  const float* xbase = x + (size_t)(rb + r_st) * (NS * NI) + c8 * 8;

  {  // stage chunk 0
    f32x4 a0 = *(const f32x4*)(xbase);
    f32x4 a1 = *(const f32x4*)(xbase + 4);
    bf16x8 u;
#pragma unroll
    for (int j = 0; j < 4; ++j) { u[j] = (__bf16)a0[j]; u[4 + j] = (__bf16)a1[j]; }
    xbuf[0][tt_st][r_st][un_st] = u;
  }
  __syncthreads();   // cold path: full drain fine

  // per-lane LDS constants
  const int sw = (ml & 7) << 1;
  int ridx[4];
#pragma unroll
  for (int kt = 0; kt < 4; ++kt) ridx[kt] = (8 * kt + 2 * g) ^ sw;  // even -> b128 ok
  const int widx = (4 * w + g) ^ sw;
  const int xidx = g ^ (ml & 3);

  f32x4 hv = {0.f, 0.f, 0.f, 0.f};
  float* optr = out + (size_t)(rb + ml) * NS * NH + 16 * w + 4 * g;

  f32x4 vxa, vxb;  // x global prefetch regs
  const f32x4 zero4 = {0.f, 0.f, 0.f, 0.f};

  // ax (= bias + x@W) for t = 0
  f32x4 axz, axh;
  {
    bf16x8 xf = xbuf[0][0][ml][xidx];
    axz = __builtin_amdgcn_mfma_f32_16x16x32_bf16(wfrag[0], xf, bias2[0], 0, 0, 0);
    axh = __builtin_amdgcn_mfma_f32_16x16x32_bf16(wfrag[1], xf, bias2[1], 0, 0, 0);
  }

  // One step. P = t&1 compile-time. Consumes ax(t); produces ax(t+1).
  // DO_STORE: store h(t) (= output row t-1) in the read shadow.
  // DO_STAGE: cvt + ds_write next x chunk in the read shadow (tt==6).
#define GRU_STEP(P, XB, TT, DO_STORE, DO_STAGE)                                            \
  {                                                                                        \
    /* 1. post-barrier read burst: 4 h frags (step t) + 1 x frag (step t+1) */             \
    const u64* hrow = &hbuf[P][ml][0];                                                     \
    bf16x8 hf0 = *(const bf16x8*)(hrow + ridx[0]);                                         \
    bf16x8 hf1 = *(const bf16x8*)(hrow + ridx[1]);                                         \
    bf16x8 hf2 = *(const bf16x8*)(hrow + ridx[2]);                                         \
    bf16x8 hf3 = *(const bf16x8*)(hrow + ridx[3]);                                         \
    const int nb_ = ((TT) == 7) ? (XB) ^ 1 : (XB);                                         \
    const int ntt = ((TT) + 1) & 7;                                                        \
    bf16x8 xf = xbuf[nb_][ntt][ml][xidx];                                                  \
    /* 2. read shadow: previous step's output store (vmem, no lgkm dep) */                 \
    if (DO_STORE) { __builtin_nontemporal_store(hv, (f32x4*)optr); optr += NH; }           \
    /* 3. read shadow: stage next x chunk (VALU cvt + ds_write behind the reads) */        \
    if (DO_STAGE) {                                                                        \
      bf16x8 u;                                                                            \
      _Pragma("unroll")                                                                    \
      for (int j = 0; j < 4; ++j) { u[j] = (__bf16)vxa[j]; u[4 + j] = (__bf16)vxb[j]; }    \
      xbuf[(XB) ^ 1][tt_st][r_st][un_st] = u;                                              \
    }                                                                                      \
    /* 4. h-MFMAs: z-gate chains first so az is ready early */                             \
    f32x4 z1 = __builtin_amdgcn_mfma_f32_16x16x32_bf16(ufrag[0][0], hf0, axz,   0, 0, 0);  \
    f32x4 z2 = __builtin_amdgcn_mfma_f32_16x16x32_bf16(ufrag[0][2], hf2, zero4, 0, 0, 0);  \
    z1 = __builtin_amdgcn_mfma_f32_16x16x32_bf16(ufrag[0][1], hf1, z1, 0, 0, 0);           \
    z2 = __builtin_amdgcn_mfma_f32_16x16x32_bf16(ufrag[0][3], hf3, z2, 0, 0, 0);           \
    f32x4 h1 = __builtin_amdgcn_mfma_f32_16x16x32_bf16(ufrag[1][0], hf0, axh,   0, 0, 0);  \
    f32x4 h2 = __builtin_amdgcn_mfma_f32_16x16x32_bf16(ufrag[1][2], hf2, zero4, 0, 0, 0);  \
    h1 = __builtin_amdgcn_mfma_f32_16x16x32_bf16(ufrag[1][1], hf1, h1, 0, 0, 0);           \
    h2 = __builtin_amdgcn_mfma_f32_16x16x32_bf16(ufrag[1][3], hf3, h2, 0, 0, 0);           \
    /* 5. ax(t+1) (independent; issues behind the h-gate MFMAs) */                         \
    axz = __builtin_amdgcn_mfma_f32_16x16x32_bf16(wfrag[0], xf, bias2[0], 0, 0, 0);        \
    axh = __builtin_amdgcn_mfma_f32_16x16x32_bf16(wfrag[1], xf, bias2[1], 0, 0, 0);        \
    /* 6. fused elementwise */                                                             \
    const f32x4 az = z1 + z2;                                                              \
    const f32x4 ah = h1 + h2;                                                              \
    f32x4 hn = gru_elem(az, ah, hv);                                                       \
    hv = hn;                                                                               \
    /* 7. publish bf16 h(t+1); short pre-barrier tail */                                   \
    hbuf[P ^ 1][ml][widx] = pack4_bf16(hn);                                                \
    lds_barrier();                                                                         \
  }

  for (int chunk = 0; chunk < NS / 8; ++chunk) {
    const int  xb   = chunk & 1;
    const bool more = (chunk + 1 < NS / 8);
    const bool st0  = (chunk > 0);

    if (xb == 0) {
      if (more) { const float* p = xbase + (size_t)(chunk + 1) * (8 * NI);
                  vxa = *(const f32x4*)(p); vxb = *(const f32x4*)(p + 4); }
      GRU_STEP(0, 0, 0, st0,  false)
      GRU_STEP(1, 0, 1, true, false)
      GRU_STEP(0, 0, 2, true, false)
      GRU_STEP(1, 0, 3, true, false)
      GRU_STEP(0, 0, 4, true, false)
      GRU_STEP(1, 0, 5, true, false)
      GRU_STEP(0, 0, 6, true, more)
      GRU_STEP(1, 0, 7, true, false)
    } else {
      if (more) { const float* p = xbase + (size_t)(chunk + 1) * (8 * NI);
                  vxa = *(const f32x4*)(p); vxb = *(const f32x4*)(p + 4); }
      GRU_STEP(0, 1, 0, true, false)
      GRU_STEP(1, 1, 1, true, false)
      GRU_STEP(0, 1, 2, true, false)
      GRU_STEP(1, 1, 3, true, false)
      GRU_STEP(0, 1, 4, true, false)
      GRU_STEP(1, 1, 5, true, false)
      GRU_STEP(0, 1, 6, true, more)
      GRU_STEP(1, 1, 7, true, false)
    }
  }

  // final output row (t = NS-1) + h_last
  __builtin_nontemporal_store(hv, (f32x4*)optr);
  const size_t lbase = (size_t)NB * NS * NH + (size_t)(rb + ml) * NH + 16 * w + 4 * g;
  *(f32x4*)(out + lbase) = hv;
}

extern "C" void kernel_launch(void* const* d_in, const int* in_sizes, int n_in,
                              void* d_out, int out_size, void* d_ws, size_t ws_size,
                              hipStream_t stream) {
  const float* x  = (const float*)d_in[0];
  // d_in[1..3] = W_r, U_r, b_r: unused (r gate never affects the output)
  const float* Wz = (const float*)d_in[4];
  const float* Uz = (const float*)d_in[5];
  const float* bz = (const float*)d_in[6];
  const float* Wh = (const float*)d_in[7];
  const float* Uh = (const float*)d_in[8];
  const float* bh = (const float*)d_in[9];
  float* out = (float*)d_out;

  gru_scan<<<dim3(NB / 16), dim3(512), 0, stream>>>(x, Wz, Uz, bz, Wh, Uh, bh, out);
}

// Round 11
// 469.006 us; speedup vs baseline: 1.6831x; 1.0679x over previous
//
#include <hip/hip_runtime.h>
#include <hip/hip_bf16.h>

typedef __bf16 bf16x8 __attribute__((ext_vector_type(8)));
typedef float  f32x4  __attribute__((ext_vector_type(4)));
typedef unsigned short u16;
typedef unsigned int   u32;
typedef unsigned int   u32x2 __attribute__((ext_vector_type(2)));
typedef unsigned long long u64;

#define NB 1024
#define NS 1024
#define NI 32
#define NH 128
#define NCH (NS / 8)

// Pack 4 f32 -> 4 bf16 (RNE) in 2 VALU via v_cvt_pk_bf16_f32.
__device__ __forceinline__ u64 pack4_bf16(f32x4 v) {
  u32 lo, hi;
  asm("v_cvt_pk_bf16_f32 %0, %1, %2" : "=v"(lo) : "v"(v[0]), "v"(v[1]));
  asm("v_cvt_pk_bf16_f32 %0, %1, %2" : "=v"(hi) : "v"(v[2]), "v"(v[3]));
  u32x2 p; p[0] = lo; p[1] = hi;
  return __builtin_bit_cast(u64, p);
}

// Barrier that drains lgkmcnt only (no vmcnt): global stores stay in flight.
__device__ __forceinline__ void lds_barrier() {
  __builtin_amdgcn_sched_barrier(0);
  asm volatile("s_waitcnt lgkmcnt(0)" ::: "memory");
  __builtin_amdgcn_s_barrier();
  asm volatile("" ::: "memory");
  __builtin_amdgcn_sched_barrier(0);
}

// Block: 512 threads = 8 waves (2/SIMD). Block owns 16 batch rows for the scan.
// Wave w computes hidden cols [16w, 16w+16).   (R3 structure = best known.)
// MFMA: D'[n][m] = sum_k U[k][n] * h[m][k]  (A' = U^T slice, B' = h^T)
//   B'-frag: lane l holds h[m=l&15][k = 32kt + 8(l>>4) + j]   (one ds_read_b128)
//   D'     : lane l holds h_new[m=l&15][n = 16w + 4(l>>4) + r]
// h ping-pongs in LDS as bf16, u64 units swizzled by unit ^ ((row&7)<<1).
// Chunk loop unrolled x2 so the x-buffer parity XB is COMPILE-TIME: all xbuf
// LDS accesses become per-lane base + offset:imm (no per-step address math).
__global__ __launch_bounds__(512, 2) void gru_scan(
    const float* __restrict__ x,
    const float* __restrict__ Wz, const float* __restrict__ Uz, const float* __restrict__ bz,
    const float* __restrict__ Wh, const float* __restrict__ Uh, const float* __restrict__ bh,
    float* __restrict__ out)
{
  __shared__ __align__(16) u64    hbuf[2][16][32];       // 8 KB
  __shared__ __align__(16) bf16x8 xbuf[2][8][16][4];     // 16 KB

  const int tid  = threadIdx.x;
  const int lane = tid & 63;
  const int w    = tid >> 6;     // wave 0..7
  const int ml   = lane & 15;    // batch row in tile
  const int g    = lane >> 4;    // k-group / reg-group
  const int rb   = blockIdx.x * 16;

  // ---- persistent weight fragments ----
  bf16x8 ufrag[2][4];   // [gate][kt]
  bf16x8 wfrag[2];      // [gate]
  f32x4  bias2[2];      // [gate], D layout
  {
    const float* Ug[2] = {Uz, Uh};
    const float* Wg[2] = {Wz, Wh};
    const float* bg[2] = {bz, bh};
    const int n0 = 16 * w + ml;   // A'-row = hidden col
#pragma unroll
    for (int gate = 0; gate < 2; ++gate) {
#pragma unroll
      for (int kt = 0; kt < 4; ++kt)
#pragma unroll
        for (int j = 0; j < 8; ++j)
          ufrag[gate][kt][j] = (__bf16)Ug[gate][(32 * kt + 8 * g + j) * NH + n0];
#pragma unroll
      for (int j = 0; j < 8; ++j)
        wfrag[gate][j] = (__bf16)Wg[gate][(8 * g + j) * NH + n0];
      const int nb = 16 * w + 4 * g;
#pragma unroll
      for (int r = 0; r < 4; ++r) bias2[gate][r] = bg[gate][nb + r];
    }
  }

  // h0 = 0
  for (int i = tid; i < 16 * 32; i += 512) hbuf[0][i >> 5][i & 31] = 0ULL;

  // ---- x staging: thread (r_st, c8) handles 8 consecutive floats (one 16B unit) ----
  const int r_st  = tid >> 5;          // 0..15
  const int c8    = tid & 31;          // 0..31 -> tt = c8>>2, unit = c8&3
  const int tt_st = c8 >> 2;
  const int un_st = (c8 & 3) ^ (r_st & 3);
  const float* xbase = x + (size_t)(rb + r_st) * (NS * NI) + c8 * 8;

  {  // stage chunk 0
    f32x4 a0 = *(const f32x4*)(xbase);
    f32x4 a1 = *(const f32x4*)(xbase + 4);
    bf16x8 u;
#pragma unroll
    for (int j = 0; j < 4; ++j) { u[j] = (__bf16)a0[j]; u[4 + j] = (__bf16)a1[j]; }
    xbuf[0][tt_st][r_st][un_st] = u;
  }
  __syncthreads();   // cold path: full drain fine

  // per-lane LDS constants
  const int sw = (ml & 7) << 1;
  int ridx[4];
#pragma unroll
  for (int kt = 0; kt < 4; ++kt) ridx[kt] = (8 * kt + 2 * g) ^ sw;  // even -> b128 ok
  const int widx = (4 * w + g) ^ sw;
  const int xidx = g ^ (ml & 3);

  f32x4 hv = {0.f, 0.f, 0.f, 0.f};
  float* optr = out + (size_t)(rb + ml) * NS * NH + 16 * w + 4 * g;

  f32x4 vxa, vxb;  // x global prefetch regs
  const float NL2E  = -1.4426950408889634f;  // -log2(e)
  const float P2L2E =  2.8853900817779268f;  //  2*log2(e)
  const f32x4 zero4 = {0.f, 0.f, 0.f, 0.f};

  // ax (= bias + x@W) for t = 0
  f32x4 axz, axh;
  {
    bf16x8 xf = xbuf[0][0][ml][xidx];
    axz = __builtin_amdgcn_mfma_f32_16x16x32_bf16(wfrag[0], xf, bias2[0], 0, 0, 0);
    axh = __builtin_amdgcn_mfma_f32_16x16x32_bf16(wfrag[1], xf, bias2[1], 0, 0, 0);
  }

  // One step. P, XB, TT all compile-time. Consumes ax(t); produces ax(t+1).
#define GRU_STEP(P, XB, TT, DO_STORE, DO_STAGE)                                            \
  {                                                                                        \
    /* h fragment reads */                                                                 \
    const u64* hrow = &hbuf[P][ml][0];                                                     \
    bf16x8 hf0 = *(const bf16x8*)(hrow + ridx[0]);                                         \
    bf16x8 hf1 = *(const bf16x8*)(hrow + ridx[1]);                                         \
    bf16x8 hf2 = *(const bf16x8*)(hrow + ridx[2]);                                         \
    bf16x8 hf3 = *(const bf16x8*)(hrow + ridx[3]);                                         \
    /* h-dependent MFMAs: 4 independent chains of 2 */                                     \
    f32x4 z1 = __builtin_amdgcn_mfma_f32_16x16x32_bf16(ufrag[0][0], hf0, axz,   0, 0, 0);  \
    f32x4 h1 = __builtin_amdgcn_mfma_f32_16x16x32_bf16(ufrag[1][0], hf0, axh,   0, 0, 0);  \
    f32x4 z2 = __builtin_amdgcn_mfma_f32_16x16x32_bf16(ufrag[0][2], hf2, zero4, 0, 0, 0);  \
    f32x4 h2 = __builtin_amdgcn_mfma_f32_16x16x32_bf16(ufrag[1][2], hf2, zero4, 0, 0, 0);  \
    z1 = __builtin_amdgcn_mfma_f32_16x16x32_bf16(ufrag[0][1], hf1, z1, 0, 0, 0);           \
    h1 = __builtin_amdgcn_mfma_f32_16x16x32_bf16(ufrag[1][1], hf1, h1, 0, 0, 0);           \
    z2 = __builtin_amdgcn_mfma_f32_16x16x32_bf16(ufrag[0][3], hf3, z2, 0, 0, 0);           \
    h2 = __builtin_amdgcn_mfma_f32_16x16x32_bf16(ufrag[1][3], hf3, h2, 0, 0, 0);           \
    const f32x4 az = z1 + z2;                                                              \
    const f32x4 ah = h1 + h2;                                                              \
    /* z = sigmoid(az); hh = tanh(ah); h += z*(hh-h)  (R3-validated form) */               \
    f32x4 hn;                                                                              \
    _Pragma("unroll")                                                                      \
    for (int r = 0; r < 4; ++r) {                                                          \
      float ez = __builtin_amdgcn_exp2f(az[r] * NL2E);                                     \
      float zz = __builtin_amdgcn_rcpf(1.f + ez);                                          \
      float eh = __builtin_amdgcn_exp2f(ah[r] * P2L2E);                                    \
      float th = 1.f - 2.f * __builtin_amdgcn_rcpf(1.f + eh);                              \
      hn[r] = __builtin_fmaf(zz, th - hv[r], hv[r]);                                       \
    }                                                                                      \
    hv = hn;                                                                               \
    /* publish bf16 h(t+1) FIRST (critical for next step's ds_read) */                     \
    hbuf[P ^ 1][ml][widx] = pack4_bf16(hn);                                                \
    if (DO_STAGE) {  /* convert + write next x chunk (compile-time XB^1) */                \
      bf16x8 u;                                                                            \
      _Pragma("unroll")                                                                    \
      for (int j = 0; j < 4; ++j) { u[j] = (__bf16)vxa[j]; u[4 + j] = (__bf16)vxb[j]; }    \
      xbuf[(XB) ^ 1][tt_st][r_st][un_st] = u;                                              \
    }                                                                                      \
    /* pre-barrier: ax(t+1) from compile-time xbuf slot */                                 \
    {                                                                                      \
      bf16x8 xf = xbuf[((TT) == 7) ? ((XB) ^ 1) : (XB)][((TT) + 1) & 7][ml][xidx];         \
      axz = __builtin_amdgcn_mfma_f32_16x16x32_bf16(wfrag[0], xf, bias2[0], 0, 0, 0);      \
      axh = __builtin_amdgcn_mfma_f32_16x16x32_bf16(wfrag[1], xf, bias2[1], 0, 0, 0);      \
    }                                                                                      \
    /* stream hidden_seq[b, t, :] — stays in flight across the barrier */                  \
    if (DO_STORE) { __builtin_nontemporal_store(hn, (f32x4*)optr); optr += NH; }           \
    lds_barrier();                                                                         \
  }

  // Chunk body: XB compile-time; loads issued at tt0, staged at tt6.
#define CHUNK_BODY(XB, CHUNK, MORE)                                                        \
  {                                                                                        \
    if (MORE) {                                                                            \
      const float* p = xbase + (size_t)((CHUNK) + 1) * (8 * NI);                           \
      vxa = *(const f32x4*)(p); vxb = *(const f32x4*)(p + 4);                              \
    }                                                                                      \
    GRU_STEP(0, XB, 0, true, false)                                                        \
    GRU_STEP(1, XB, 1, true, false)                                                        \
    GRU_STEP(0, XB, 2, true, false)                                                        \
    GRU_STEP(1, XB, 3, true, false)                                                        \
    GRU_STEP(0, XB, 4, true, false)                                                        \
    GRU_STEP(1, XB, 5, true, false)                                                        \
    GRU_STEP(0, XB, 6, true, (MORE))                                                       \
    GRU_STEP(1, XB, 7, true, false)                                                        \
  }

  for (int cp = 0; cp < NCH / 2; ++cp) {
    const int  c0 = 2 * cp;
    const bool m1 = (c0 + 2 < NCH);
    CHUNK_BODY(0, c0,     true)   // even chunk: chunk+1 always exists
    CHUNK_BODY(1, c0 + 1, m1)     // odd chunk
  }

  // h_last
  const size_t lbase = (size_t)NB * NS * NH + (size_t)(rb + ml) * NH + 16 * w + 4 * g;
  *(f32x4*)(out + lbase) = hv;
}

extern "C" void kernel_launch(void* const* d_in, const int* in_sizes, int n_in,
                              void* d_out, int out_size, void* d_ws, size_t ws_size,
                              hipStream_t stream) {
  const float* x  = (const float*)d_in[0];
  // d_in[1..3] = W_r, U_r, b_r: unused (r gate never affects the output)
  const float* Wz = (const float*)d_in[4];
  const float* Uz = (const float*)d_in[5];
  const float* bz = (const float*)d_in[6];
  const float* Wh = (const float*)d_in[7];
  const float* Uh = (const float*)d_in[8];
  const float* bh = (const float*)d_in[9];
  float* out = (float*)d_out;

  gru_scan<<<dim3(NB / 16), dim3(512), 0, stream>>>(x, Wz, Uz, bz, Wh, Uh, bh, out);
}